// Round 23
// baseline (41.456 us; speedup 1.0000x reference)
//
#include <hip/hip_runtime.h>

#define B_SZ 256
#define N_SZ 2000
#define N_PAD 2048
#define D_SZ 512
#define C_SZ 100
#define BT 4              // batch rows per block
#define NB4 (B_SZ / BT)   // 64 b-tiles
#define NCH 32            // n-chunks of 64
#define CHUNK 64          // n's per block
#define D4 (D_SZ / 4)     // 128 float4 per row

typedef __fp16 h2 __attribute__((ext_vector_type(2)));

// ---------------------------------------------------------------------------
// prep: labels one-hot -> class idx (padded to 2048 with 0)
// ---------------------------------------------------------------------------
__global__ void prep_kernel(const float* __restrict__ labels,
                            int* __restrict__ idx) {
    int n = blockIdx.x * 256 + threadIdx.x;  // 8 blocks x 256 = 2048
    int c = 0;
    if (n < N_SZ) {
        const float4* row = (const float4*)(labels + (size_t)n * C_SZ);
#pragma unroll
        for (int j = 0; j < C_SZ / 4; ++j) {
            float4 v = row[j];
            if (v.x > 0.5f) c = 4 * j + 0;
            if (v.y > 0.5f) c = 4 * j + 1;
            if (v.z > 0.5f) c = 4 * j + 2;
            if (v.w > 0.5f) c = 4 * j + 3;
        }
    }
    if (n < N_PAD) idx[n] = c;
}

// ---------------------------------------------------------------------------
// Main (one-pass, lane-owns-d). Lane l owns d in [8l, 8l+8) -> the whole
// D=512 lives in one wave; support rows read DIRECTLY (f32, coalesced 2KB)
// -- no transposed copy, no setup kernel, no S16 partial round-trip.
// Wave sweeps 16 n's; per (n, 4b) the 8-d partials are packed f16 to LDS;
// block transpose-reduce (padded rows, conflict-free; f32 accumulation)
// produces full logits -> sigmoid -> LDS class bins -> tmp slice.
// ---------------------------------------------------------------------------
__global__ __launch_bounds__(256, 4) void score_kernel(
    const float4* __restrict__ inp4,   // [B][D4]
    const float4* __restrict__ sup4,   // [N][D4]
    const float4* __restrict__ w4,     // [D4]
    const int* __restrict__ idx,       // [N_PAD]
    const float* __restrict__ bias_p,  // [1]
    float* __restrict__ tmp,           // [NCH][NB4][BT][C_SZ]
    float* __restrict__ tmpc)          // [NCH][C_SZ] (b-tile 0 only)
{
    __shared__ unsigned bufA[CHUNK][65];  // pk(acc0,acc1), padded rows
    __shared__ unsigned bufB[CHUNK][65];  // pk(acc2,acc3)
    __shared__ float2 qA[4][64];
    __shared__ float2 qB[4][64];
    __shared__ float sums[BT][C_SZ];
    __shared__ float cnts[C_SZ];

    int tid  = threadIdx.x;
    int lane = tid & 63;
    int wv   = tid >> 6;
    int b0   = blockIdx.x * BT;
    int chunk = blockIdx.y * CHUNK;

    if (tid < C_SZ) {
        sums[0][tid] = 0.f; sums[1][tid] = 0.f;
        sums[2][tid] = 0.f; sums[3][tid] = 0.f;
        cnts[tid] = 0.f;
    }

    unsigned vz = 0;                 // opaque zero: force vector path
    asm volatile("" : "+v"(vz));

    // inputs + w: lane's 8 d's for 4 b rows = 10 float4 = 40 VGPRs, one-time
    float4 af[BT][2];
    float4 wf[2];
#pragma unroll
    for (int i = 0; i < BT; ++i) {
        const float4* ap = inp4 + (size_t)(b0 + i) * D4 + 2 * lane + vz;
        af[i][0] = ap[0];
        af[i][1] = ap[1];
    }
    {
        const float4* wp = w4 + 2 * lane + vz;
        wf[0] = wp[0];
        wf[1] = wp[1];
    }

    // ---- n-sweep: 16 n's per wave, support rows coalesced, 1-deep prefetch
    const float4* sp = sup4 + 2 * lane + vz;
    int n0 = chunk + 16 * wv;
    {
        int nc = min(n0, N_SZ - 1);
        float4 s0 = sp[(size_t)nc * D4];
        float4 s1 = sp[(size_t)nc * D4 + 1];
#pragma unroll 1
        for (int k = 0; k < 16; ++k) {
            float4 c0 = s0, c1 = s1;
            if (k < 15) {
                int nn = min(n0 + k + 1, N_SZ - 1);
                s0 = sp[(size_t)nn * D4];
                s1 = sp[(size_t)nn * D4 + 1];
            }
            float acc[BT];
#pragma unroll
            for (int i = 0; i < BT; ++i) {
                float a;
                a  = wf[0].x * fabsf(af[i][0].x - c0.x);
                a += wf[0].y * fabsf(af[i][0].y - c0.y);
                a += wf[0].z * fabsf(af[i][0].z - c0.z);
                a += wf[0].w * fabsf(af[i][0].w - c0.w);
                a += wf[1].x * fabsf(af[i][1].x - c1.x);
                a += wf[1].y * fabsf(af[i][1].y - c1.y);
                a += wf[1].z * fabsf(af[i][1].z - c1.z);
                a += wf[1].w * fabsf(af[i][1].w - c1.w);
                acc[i] = a;
            }
            h2 p0 = __builtin_amdgcn_cvt_pkrtz(acc[0], acc[1]);
            h2 p1 = __builtin_amdgcn_cvt_pkrtz(acc[2], acc[3]);
            bufA[16 * wv + k][lane] = __builtin_bit_cast(unsigned, p0);
            bufB[16 * wv + k][lane] = __builtin_bit_cast(unsigned, p1);
        }
    }
    __syncthreads();

    // ---- phase 1: quarter-sums over lanes (f32 accumulation)
    {
        int nl = tid & 63, q = tid >> 6;
        float a0 = 0.f, a1 = 0.f, b2 = 0.f, b3 = 0.f;
#pragma unroll
        for (int j = 16 * q; j < 16 * q + 16; ++j) {
            h2 ua = __builtin_bit_cast(h2, bufA[nl][j]);
            h2 ub = __builtin_bit_cast(h2, bufB[nl][j]);
            a0 += (float)ua.x; a1 += (float)ua.y;
            b2 += (float)ub.x; b3 += (float)ub.y;
        }
        qA[q][nl] = make_float2(a0, a1);
        qB[q][nl] = make_float2(b2, b3);
    }
    __syncthreads();

    // ---- phase 2: final sum + sigmoid + class binning (threads 0..63)
    if (tid < 64) {
        float2 A = qA[0][tid], Bv = qB[0][tid];
#pragma unroll
        for (int q = 1; q < 4; ++q) {
            A.x += qA[q][tid].x; A.y += qA[q][tid].y;
            Bv.x += qB[q][tid].x; Bv.y += qB[q][tid].y;
        }
        int n = chunk + tid;
        if (n < N_SZ) {
            float bias = *bias_p;
            int c = idx[n];
            float lg[BT] = {A.x, A.y, Bv.x, Bv.y};
#pragma unroll
            for (int i = 0; i < BT; ++i) {
                float sg = 1.0f / (1.0f + __expf(-(lg[i] + bias)));
                atomicAdd(&sums[i][c], sg);
            }
            if (blockIdx.x == 0) atomicAdd(&cnts[c], 1.0f);
        }
    }
    __syncthreads();

    // ---- write per-(chunk, b-tile) class partials (fully written -> no memset)
    float* tb = tmp + (((size_t)blockIdx.y * NB4 + blockIdx.x) * BT) * C_SZ;
    for (int t = tid; t < BT * C_SZ; t += 256)
        tb[t] = sums[t / C_SZ][t % C_SZ];
    if (blockIdx.x == 0 && tid < C_SZ)
        tmpc[(size_t)blockIdx.y * C_SZ + tid] = cnts[tid];
}

// ---------------------------------------------------------------------------
// div: out[b][c] = divide_no_nan(sum_ch tmp, sum_ch tmpc)
// ---------------------------------------------------------------------------
__global__ void div_kernel(const float* __restrict__ tmp,
                           const float* __restrict__ tmpc,
                           float* __restrict__ out) {
    int b = blockIdx.x, t = threadIdx.x;
    if (t < C_SZ) {
        int b4 = b >> 2, i = b & 3;
        float s = 0.f, cnt = 0.f;
#pragma unroll
        for (int ch = 0; ch < NCH; ++ch) {
            s   += tmp[(((size_t)ch * NB4 + b4) * BT + i) * C_SZ + t];
            cnt += tmpc[(size_t)ch * C_SZ + t];
        }
        out[(size_t)b * C_SZ + t] = (cnt != 0.f) ? s / cnt : 0.f;
    }
}

extern "C" void kernel_launch(void* const* d_in, const int* in_sizes, int n_in,
                              void* d_out, int out_size, void* d_ws, size_t ws_size,
                              hipStream_t stream) {
    const float* inputs  = (const float*)d_in[0]; // [B, D]
    const float* support = (const float*)d_in[1]; // [N, D]
    const float* labels  = (const float*)d_in[2]; // [N, C]
    const float* w       = (const float*)d_in[3]; // [D]
    const float* bias    = (const float*)d_in[4]; // [1]
    float* out = (float*)d_out;                   // [B, C]

    // ws: idx@0 (8KB) | tmp@16KB (3.28MB) | tmpc@4MB (12.8KB).
    // All regions fully written before read; no memsets.
    int*   idx  = (int*)d_ws;
    float* tmp  = (float*)((char*)d_ws + 16384);
    float* tmpc = (float*)((char*)d_ws + 4 * 1024 * 1024);

    prep_kernel<<<dim3(8), dim3(256), 0, stream>>>(labels, idx);

    dim3 grid(NB4, NCH); // 64 x 32 = 2048 blocks
    score_kernel<<<grid, dim3(256), 0, stream>>>(
        (const float4*)inputs, (const float4*)support, (const float4*)w,
        idx, bias, tmp, tmpc);

    div_kernel<<<dim3(B_SZ), dim3(128), 0, stream>>>(tmp, tmpc, out);
}

// Round 24
// 38.180 us; speedup vs baseline: 1.0858x; 1.0858x over previous
//
#include <hip/hip_runtime.h>

#define B_SZ 256
#define N_SZ 2000
#define N_PAD 2048
#define D_SZ 512
#define C_SZ 100
#define BT 4             // batch rows per block
#define JW 4             // H8 groups (8 d's each) per block = 32 d's
#define ZSPLIT 16        // D_SZ / 32
#define NSPLIT 2         // n-sweep halves (blockIdx.z) -> 8 waves/SIMD
#define D4 (D_SZ / 4)
#define DC8 (D_SZ / 8)   // 64 H8 rows in supH

typedef __fp16 h2 __attribute__((ext_vector_type(2)));

struct alignas(16) H8 { h2 x, y, z, w; };  // 8 consecutive halves
struct alignas(8)  H4 { h2 lo, hi; };      // 4 consecutive halves

static __device__ __forceinline__ h2 habs2(h2 v) {
    unsigned u = __builtin_bit_cast(unsigned, v) & 0x7FFF7FFFu;
    return __builtin_bit_cast(h2, u);
}

#if __has_builtin(__builtin_amdgcn_fdot2)
static __device__ __forceinline__ float DOT2(h2 d, h2 wv, float c) {
    return __builtin_amdgcn_fdot2(d, wv, c, false);
}
#else
static __device__ __forceinline__ float DOT2(h2 d, h2 wv, float c) {
    return c + (float)d.x * (float)wv.x + (float)d.y * (float)wv.y;
}
#endif

// ---------------------------------------------------------------------------
// Fused setup: [0,512) transpose+convert support | [512,640) inputs f32->f16
// | [640,648) labels->idx | [648] w->f16.
// ---------------------------------------------------------------------------
__global__ void setup_kernel(const float* __restrict__ labels,
                             const float* __restrict__ inputs,
                             const float* __restrict__ w,
                             const float4* __restrict__ sup4,
                             int* __restrict__ idx,
                             H4* __restrict__ inpH4,
                             H4* __restrict__ wH4,
                             H8* __restrict__ supH) {
    int bid = blockIdx.x, tid = threadIdx.x;
    if (bid < 512) {                     // support transpose+convert
        int t   = bid * 256 + tid;       // t = n * 64 + dc8
        int n   = t >> 6;
        int dc8 = t & 63;
        H8 o = {};
        if (n < N_SZ) {
            float4 p = sup4[(size_t)n * D4 + 2 * dc8];
            float4 q = sup4[(size_t)n * D4 + 2 * dc8 + 1];
            o.x = __builtin_amdgcn_cvt_pkrtz(p.x, p.y);
            o.y = __builtin_amdgcn_cvt_pkrtz(p.z, p.w);
            o.z = __builtin_amdgcn_cvt_pkrtz(q.x, q.y);
            o.w = __builtin_amdgcn_cvt_pkrtz(q.z, q.w);
        }
        supH[(size_t)dc8 * N_PAD + n] = o;
    } else if (bid < 640) {              // inputs convert
        int i4 = (bid - 512) * 256 + tid;    // 32768 float4
        float4 v = ((const float4*)inputs)[i4];
        H4 o;
        o.lo = __builtin_amdgcn_cvt_pkrtz(v.x, v.y);
        o.hi = __builtin_amdgcn_cvt_pkrtz(v.z, v.w);
        inpH4[i4] = o;
    } else if (bid < 648) {              // label one-hot -> class idx
        int n = (bid - 640) * 256 + tid;
        if (n < N_SZ) {
            const float4* row = (const float4*)(labels + (size_t)n * C_SZ);
            int c = 0;
#pragma unroll
            for (int j = 0; j < C_SZ / 4; ++j) {
                float4 v = row[j];
                if (v.x > 0.5f) c = 4 * j + 0;
                if (v.y > 0.5f) c = 4 * j + 1;
                if (v.z > 0.5f) c = 4 * j + 2;
                if (v.w > 0.5f) c = 4 * j + 3;
            }
            idx[n] = c;
        }
    } else {                             // w convert (128 float4)
        if (tid < D_SZ / 4) {
            float4 v = ((const float4*)w)[tid];
            H4 o;
            o.lo = __builtin_amdgcn_cvt_pkrtz(v.x, v.y);
            o.hi = __builtin_amdgcn_cvt_pkrtz(v.z, v.w);
            wH4[tid] = o;
        }
    }
}

// ---------------------------------------------------------------------------
// Main — best-known configuration (r21): f16 packed math (pk_sub + and(abs)
// + v_dot2_f32_f16, 1.5 instr/elem, f32 accumulation), af/wf loaded once
// via the vz vector-path trick, coalesced support stream with 1-deep
// prefetch, NSPLIT=2 grid (2048 blocks -> 8 waves/SIMD at VGPR=64),
// f16 partial stores (16MB round-trip).
// ---------------------------------------------------------------------------
__global__ __launch_bounds__(256, 4) void score_kernel(
    const H8* __restrict__ inpH8,   // [B][DC8]
    const H8* __restrict__ supH,    // [DC8][N_PAD]
    const H8* __restrict__ wH8,     // [DC8]
    __fp16* __restrict__ S16)       // [ZSPLIT][B][N_PAD]
{
    int tid = threadIdx.x;
    int b0  = blockIdx.x * BT;
    int dc0 = blockIdx.y * JW;          // H8-row base (32 d's)
    int nh  = blockIdx.z * (N_PAD / NSPLIT);  // n-half base

    unsigned vz = 0;                // opaque zero: force vector regs
    asm volatile("" : "+v"(vz));

    H8 af[BT][JW];
    H8 wf[JW];
#pragma unroll
    for (int i = 0; i < BT; ++i) {
        const H8* ap = inpH8 + (size_t)(b0 + i) * DC8 + dc0 + vz;
#pragma unroll
        for (int j = 0; j < JW; ++j) af[i][j] = ap[j];
    }
    {
        const H8* wp = wH8 + dc0 + vz;
#pragma unroll
        for (int j = 0; j < JW; ++j) wf[j] = wp[j];
    }

    const H8* sp0 = supH + (size_t)(dc0 + 0) * N_PAD + nh + tid;
    const H8* sp1 = supH + (size_t)(dc0 + 1) * N_PAD + nh + tid;
    const H8* sp2 = supH + (size_t)(dc0 + 2) * N_PAD + nh + tid;
    const H8* sp3 = supH + (size_t)(dc0 + 3) * N_PAD + nh + tid;

    __fp16* Sp0 = S16 + ((size_t)blockIdx.y * B_SZ + b0) * N_PAD + nh + tid;

#define STEP(J, SV)                                                  \
    {                                                                \
        H8 wv = wf[J];                                               \
        _Pragma("unroll") for (int i = 0; i < BT; ++i) {             \
            H8 a = af[i][J];                                         \
            acc[i] = DOT2(habs2(a.x - SV.x), wv.x, acc[i]);          \
            acc[i] = DOT2(habs2(a.y - SV.y), wv.y, acc[i]);          \
            acc[i] = DOT2(habs2(a.z - SV.z), wv.z, acc[i]);          \
            acc[i] = DOT2(habs2(a.w - SV.w), wv.w, acc[i]);          \
        }                                                            \
    }

    H8 sv0 = sp0[0], sv1 = sp1[0], sv2 = sp2[0], sv3 = sp3[0];

#define NHALF (N_PAD / NSPLIT)
#pragma unroll 1
    for (int n0 = 0; n0 < NHALF - 256; n0 += 256) {
        float acc[BT] = {0.f, 0.f, 0.f, 0.f};
        H8 nx0 = sp0[n0 + 256];
        STEP(0, sv0);
        H8 nx1 = sp1[n0 + 256];
        STEP(1, sv1);
        H8 nx2 = sp2[n0 + 256];
        STEP(2, sv2);
        H8 nx3 = sp3[n0 + 256];
        STEP(3, sv3);
#pragma unroll
        for (int i = 0; i < BT; ++i)
            Sp0[(size_t)i * N_PAD + n0] = (__fp16)acc[i];
        sv0 = nx0; sv1 = nx1; sv2 = nx2; sv3 = nx3;
    }
    {   // epilogue n-step
        float acc[BT] = {0.f, 0.f, 0.f, 0.f};
        STEP(0, sv0); STEP(1, sv1); STEP(2, sv2); STEP(3, sv3);
#pragma unroll
        for (int i = 0; i < BT; ++i)
            Sp0[(size_t)i * N_PAD + (NHALF - 256)] = (__fp16)acc[i];
    }
#undef STEP
#undef NHALF
}

// ---------------------------------------------------------------------------
// Aggregate: one 1024-thread block per batch row. Sum 16 f16 partials +
// bias -> sigmoid -> LDS class bins -> divide_no_nan.
// ---------------------------------------------------------------------------
__global__ void agg_kernel(const __fp16* __restrict__ S16,
                           const int* __restrict__ idx,
                           const float* __restrict__ bias_p,
                           float* __restrict__ out) {
    __shared__ float sums[C_SZ];
    __shared__ float cnts[C_SZ];
    int b = blockIdx.x;
    int t = threadIdx.x;
    if (t < C_SZ) { sums[t] = 0.f; cnts[t] = 0.f; }
    __syncthreads();
    float bias = *bias_p;
    for (int n = t; n < N_SZ; n += 1024) {
        float logit = bias;
#pragma unroll
        for (int z = 0; z < ZSPLIT; ++z)
            logit += (float)S16[((size_t)z * B_SZ + b) * N_PAD + n];
        float s = 1.0f / (1.0f + __expf(-logit));
        int c = idx[n];
        atomicAdd(&sums[c], s);
        atomicAdd(&cnts[c], 1.0f);
    }
    __syncthreads();
    if (t < C_SZ) {
        float cnt = cnts[t];
        out[(size_t)b * C_SZ + t] = (cnt != 0.f) ? sums[t] / cnt : 0.f;
    }
}

extern "C" void kernel_launch(void* const* d_in, const int* in_sizes, int n_in,
                              void* d_out, int out_size, void* d_ws, size_t ws_size,
                              hipStream_t stream) {
    const float* inputs  = (const float*)d_in[0]; // [B, D]
    const float* support = (const float*)d_in[1]; // [N, D]
    const float* labels  = (const float*)d_in[2]; // [N, C]
    const float* w       = (const float*)d_in[3]; // [D]
    const float* bias    = (const float*)d_in[4]; // [1]
    float* out = (float*)d_out;                   // [B, C]

    // ws layout (bytes): idx@0 (8K) | wH@8K (1K) | inpH@16K (256K) |
    // supH@512K (2M) | S16@4M (16MB f16). All written before read.
    int*     idx  = (int*)d_ws;
    H4*      wH4  = (H4*)((char*)d_ws + 8192);
    H4*      inpH = (H4*)((char*)d_ws + 16384);
    H8*      supH = (H8*)((char*)d_ws + 524288);
    __fp16*  S16  = (__fp16*)((char*)d_ws + 4 * 1024 * 1024);

    setup_kernel<<<dim3(649), dim3(256), 0, stream>>>(
        labels, inputs, w, (const float4*)support, idx, inpH, wH4, supH);

    dim3 grid(B_SZ / BT, ZSPLIT, NSPLIT); // 64 x 16 x 2 = 2048 blocks
    score_kernel<<<grid, dim3(256), 0, stream>>>(
        (const H8*)inpH, supH, (const H8*)wH4, S16);

    agg_kernel<<<dim3(B_SZ), dim3(1024), 0, stream>>>(S16, idx, bias, out);
}